// Round 1
// baseline (196.819 us; speedup 1.0000x reference)
//
#include <hip/hip_runtime.h>

#define VOCAB 50000
#define EMBED 256
#define NB    16
#define NC    64
#define NS    512
#define UNK   1

// scores[b*NC+c] = sum_{j: q[b,j]>0} dot(emb[src[bc,j]], emb[q[b,j]])
// One block per (b,c). 256 threads = 4 waves; wave w handles j = w, w+4, ...
// Each lane loads float4 (16B) of the 256-float embedding rows -> 1KB/row/wave,
// fully coalesced. Mask check is wave-uniform (depends only on b,j).
__global__ __launch_bounds__(256) void scores_kernel(
    const int* __restrict__ src, const int* __restrict__ q,
    const float* __restrict__ emb, float* __restrict__ scores)
{
    const int bc   = blockIdx.x;       // 0..1023
    const int b    = bc >> 6;          // bc / NC
    const int tid  = threadIdx.x;
    const int wave = tid >> 6;         // 0..3
    const int lane = tid & 63;         // float4 index into 256-float row (64 x 16B)

    const float4* __restrict__ emb4 = (const float4*)emb;
    const int* __restrict__ srow = src + (size_t)bc * NS;
    const int* __restrict__ qrow = q   + (size_t)b  * NS;

    float acc = 0.f;
    for (int j = wave; j < NS; j += 4) {
        const int qv = qrow[j];
        if (qv > 0) {                              // wave-uniform branch
            const int sv  = srow[j];
            const int qid = (qv >= VOCAB) ? UNK : qv;
            const int sid = (sv >= VOCAB) ? UNK : sv;
            const float4 a  = emb4[(size_t)sid * (EMBED / 4) + lane];
            const float4 bq = emb4[(size_t)qid * (EMBED / 4) + lane];
            acc += a.x * bq.x + a.y * bq.y + a.z * bq.z + a.w * bq.w;
        }
    }

    // wave reduce (64 lanes)
    for (int off = 32; off > 0; off >>= 1)
        acc += __shfl_down(acc, off, 64);

    __shared__ float red[4];
    if (lane == 0) red[wave] = acc;
    __syncthreads();
    if (tid == 0)
        scores[bc] = red[0] + red[1] + red[2] + red[3];
}

// One block per b, 64 threads = the C dimension.
// softmax(scores[b,:]) -> out[8192 + b*64 + c]  (float32)
// argmax -> copy sources[b, top, :] (512 ids) -> out[b*512 .. +511] as float32
__global__ __launch_bounds__(64) void finalize_kernel(
    const float* __restrict__ scores, const int* __restrict__ src,
    float* __restrict__ out)
{
    const int b = blockIdx.x;   // 0..15
    const int t = threadIdx.x;  // 0..63 == c

    const float s = scores[b * NC + t];

    // max over 64 lanes (exact; no arithmetic error)
    float m = s;
    for (int off = 32; off > 0; off >>= 1)
        m = fmaxf(m, __shfl_xor(m, off, 64));

    const float e = expf(s - m);
    float sum = e;
    for (int off = 32; off > 0; off >>= 1)
        sum += __shfl_xor(sum, off, 64);

    out[NB * NS + b * NC + t] = e / sum;   // sims, after the 8192 out_sources

    // first-occurrence argmax == jnp.argmax tie rule
    const unsigned long long ballot = __ballot(s == m);
    const int top = __ffsll(ballot) - 1;

    const int* __restrict__ srow = src + ((size_t)b * NC + top) * NS;
    for (int j = t; j < NS; j += 64)
        out[b * NS + j] = (float)srow[j];
}

extern "C" void kernel_launch(void* const* d_in, const int* in_sizes, int n_in,
                              void* d_out, int out_size, void* d_ws, size_t ws_size,
                              hipStream_t stream) {
    const int*   src = (const int*)d_in[0];    // [NB*NC, NS] int32
    const int*   q   = (const int*)d_in[1];    // [NB, NS] int32
    // d_in[2] = context_len scalar (== NC, compile-time constant here)
    const float* emb = (const float*)d_in[3];  // [VOCAB, EMBED] f32

    float* out    = (float*)d_out;             // 8192 out_sources + 1024 sims, all f32
    float* scores = (float*)d_ws;              // 1024 floats scratch

    scores_kernel<<<NB * NC, 256, 0, stream>>>(src, q, emb, scores);
    finalize_kernel<<<NB, 64, 0, stream>>>(scores, src, out);
}

// Round 2
// 150.768 us; speedup vs baseline: 1.3054x; 1.3054x over previous
//
#include <hip/hip_runtime.h>

#define VOCAB 50000
#define EMBED 256
#define NB    16
#define NC    64
#define NS    512
#define UNK   1

#define CTILE 8              // c's per block
#define JT    8              // j tiles
#define JLEN  (NS / JT)      // 64 j's per tile

// Partial scores: grid = NB * (NC/CTILE) * JT = 16*8*8 = 1024 blocks, 256 thr.
// Block (b, ct, jt): for 8 c's and 64 j's, acc[i] += <emb[src[b,c0+i,j]], emb[q[b,j]]>.
// Each j-iter: 1 query float4 load + 8 independent source gathers -> 8x MLP,
// query rows read once per 8 c's (was once per c).
__global__ __launch_bounds__(256) void scores_kernel(
    const int* __restrict__ src, const int* __restrict__ q,
    const float* __restrict__ emb, float* __restrict__ partial)
{
    const int x  = blockIdx.x;
    const int jt = x & (JT - 1);
    const int ct = (x >> 3) & (NC / CTILE - 1);
    const int b  = x >> 6;
    const int c0 = ct * CTILE;
    const int j0 = jt * JLEN;

    const int tid  = threadIdx.x;
    const int wave = tid >> 6;
    const int lane = tid & 63;          // float4 index into 256-float row

    const float4* __restrict__ emb4 = (const float4*)emb;
    const int* __restrict__ qrow = q + (size_t)b * NS;
    const int* __restrict__ srow = src + ((size_t)b * NC + c0) * NS;

    float acc[CTILE];
#pragma unroll
    for (int i = 0; i < CTILE; i++) acc[i] = 0.f;

    for (int j = j0 + wave; j < j0 + JLEN; j += 4) {
        const int qv = qrow[j];
        if (qv > 0) {                                   // wave-uniform
            const int qid = (qv >= VOCAB) ? UNK : qv;
            const float4 eq = emb4[(size_t)qid * (EMBED / 4) + lane];

            int sid[CTILE];
#pragma unroll
            for (int i = 0; i < CTILE; i++) {
                const int sv = srow[(size_t)i * NS + j];
                sid[i] = (sv >= VOCAB) ? UNK : sv;
            }
            float4 a[CTILE];
#pragma unroll
            for (int i = 0; i < CTILE; i++)
                a[i] = emb4[(size_t)sid[i] * (EMBED / 4) + lane];
#pragma unroll
            for (int i = 0; i < CTILE; i++)
                acc[i] += a[i].x * eq.x + a[i].y * eq.y + a[i].z * eq.z + a[i].w * eq.w;
        }
    }

    // wave reduce all 8 accumulators
#pragma unroll
    for (int off = 32; off > 0; off >>= 1)
#pragma unroll
        for (int i = 0; i < CTILE; i++)
            acc[i] += __shfl_down(acc[i], off, 64);

    __shared__ float red[4][CTILE];
    if (lane == 0)
#pragma unroll
        for (int i = 0; i < CTILE; i++) red[wave][i] = acc[i];
    __syncthreads();

    if (tid < CTILE) {
        const float s = red[0][tid] + red[1][tid] + red[2][tid] + red[3][tid];
        partial[(size_t)jt * (NB * NC) + b * NC + c0 + tid] = s;
    }
}

// One block per b, 256 threads. Wave 0: sum JT partials -> softmax -> sims,
// first-occurrence argmax. Then all 256 threads copy the winning source row.
__global__ __launch_bounds__(256) void finalize_kernel(
    const float* __restrict__ partial, const int* __restrict__ src,
    float* __restrict__ out)
{
    const int b   = blockIdx.x;
    const int tid = threadIdx.x;

    __shared__ int top_sh;

    if (tid < 64) {
        const int c = tid;
        float s = 0.f;
#pragma unroll
        for (int jt = 0; jt < JT; jt++)
            s += partial[(size_t)jt * (NB * NC) + b * NC + c];

        float m = s;
#pragma unroll
        for (int off = 32; off > 0; off >>= 1)
            m = fmaxf(m, __shfl_xor(m, off, 64));

        const float e = expf(s - m);
        float sum = e;
#pragma unroll
        for (int off = 32; off > 0; off >>= 1)
            sum += __shfl_xor(sum, off, 64);

        out[NB * NS + b * NC + c] = e / sum;     // sims after 8192 out_sources

        const unsigned long long ballot = __ballot(s == m);
        if (tid == 0) top_sh = __ffsll(ballot) - 1;
    }
    __syncthreads();

    const int top = top_sh;
    const int* __restrict__ srow = src + ((size_t)b * NC + top) * NS;
#pragma unroll
    for (int j = tid; j < NS; j += 256)
        out[b * NS + j] = (float)srow[j];
}

extern "C" void kernel_launch(void* const* d_in, const int* in_sizes, int n_in,
                              void* d_out, int out_size, void* d_ws, size_t ws_size,
                              hipStream_t stream) {
    const int*   src = (const int*)d_in[0];    // [NB*NC, NS] int32
    const int*   q   = (const int*)d_in[1];    // [NB, NS] int32
    const float* emb = (const float*)d_in[3];  // [VOCAB, EMBED] f32

    float* out     = (float*)d_out;            // 8192 out_sources + 1024 sims (f32)
    float* partial = (float*)d_ws;             // [JT][NB*NC] = 8192 floats

    scores_kernel<<<NB * (NC / CTILE) * JT, 256, 0, stream>>>(src, q, emb, partial);
    finalize_kernel<<<NB, 256, 0, stream>>>(partial, src, out);
}